// Round 1
// baseline (7344.823 us; speedup 1.0000x reference)
//
#include <hip/hip_runtime.h>
#include <stdint.h>

typedef __attribute__((ext_vector_type(8))) short v8s;
typedef __attribute__((ext_vector_type(4))) float v4f;

#define MFMA(a, b, c) __builtin_amdgcn_mfma_f32_16x16x32_bf16((a), (b), (c), 0, 0, 0)

__device__ __forceinline__ unsigned short f2bf(float x) {
    unsigned u = __float_as_uint(x);
    return (unsigned short)((u + 0x7fffu + ((u >> 16) & 1u)) >> 16);
}
__device__ __forceinline__ uint2 pack4(float a, float b, float c, float d) {
    uint2 r;
    r.x = (unsigned)f2bf(a) | ((unsigned)f2bf(b) << 16);
    r.y = (unsigned)f2bf(c) | ((unsigned)f2bf(d) << 16);
    return r;
}

// ---------------------------------------------------------------------------
// Weight conversion: attn/comb hx-halves, gru wih/whh, conv weights (im2col
// layout w2[o][tap*2048+c]) -> bf16
// ---------------------------------------------------------------------------
__global__ __launch_bounds__(256) void k_convert(
    const float* __restrict__ attn_w, const float* __restrict__ comb_w,
    const float* __restrict__ gwih, const float* __restrict__ gwhh,
    const float* __restrict__ conv_w,
    unsigned short* __restrict__ awh, unsigned short* __restrict__ cwh,
    unsigned short* __restrict__ wih, unsigned short* __restrict__ whh,
    unsigned short* __restrict__ w2)
{
    const int S0 = 512 * 512;
    const int S1 = S0 + 512 * 512;
    const int S2 = S1 + 1536 * 512;
    const int S3 = S2 + 1536 * 512;
    const int S4 = S3 + 32 * 18432;
    for (int i = blockIdx.x * 256 + threadIdx.x; i < S4; i += gridDim.x * 256) {
        if (i < S0) {
            int n = i >> 9, k = i & 511;
            awh[i] = f2bf(attn_w[n * 1024 + 512 + k]);
        } else if (i < S1) {
            int j = i - S0; int n = j >> 9, k = j & 511;
            cwh[j] = f2bf(comb_w[n * 1024 + 512 + k]);
        } else if (i < S2) {
            int j = i - S1;
            wih[j] = f2bf(gwih[j]);
        } else if (i < S3) {
            int j = i - S2;
            whh[j] = f2bf(gwhh[j]);
        } else {
            int j = i - S3;
            int o = j / 18432, r = j - o * 18432;
            int tap = r >> 11, c = r & 2047;
            w2[j] = f2bf(conv_w[(o * 2048 + c) * 9 + tap]);
        }
    }
}

// ---------------------------------------------------------------------------
// features [256][2048][64] fp32 -> featT [256*64][2048] bf16 (channel-minor)
// ---------------------------------------------------------------------------
__global__ __launch_bounds__(256) void k_tfeat(const float* __restrict__ feat,
                                               unsigned short* __restrict__ featT)
{
    __shared__ float tile[64][65];
    const int b = blockIdx.x >> 5, c0 = (blockIdx.x & 31) << 6;
    for (int i = threadIdx.x; i < 4096; i += 256) {
        int cl = i >> 6, p = i & 63;
        tile[cl][p] = feat[((size_t)(b * 2048 + c0 + cl)) * 64 + p];
    }
    __syncthreads();
    for (int i = threadIdx.x; i < 4096; i += 256) {
        int pl = i >> 6, cl = i & 63;
        featT[((size_t)(b * 64 + pl)) * 2048 + c0 + cl] = f2bf(tile[cl][pl]);
    }
}

// ---------------------------------------------------------------------------
// Implicit-GEMM conv: C[m=b*64+p][o] over K = 9 taps * 2048 ch, pad=1.
// Output written in flatten-order conv_flat[b][o*64+p], + conv_b.
// ---------------------------------------------------------------------------
__global__ __launch_bounds__(256) void k_conv(const unsigned short* __restrict__ featT,
                                              const unsigned short* __restrict__ w2,
                                              const float* __restrict__ conv_b,
                                              float* __restrict__ out)
{
    __shared__ short As[128 * 40];
    __shared__ short Bs[32 * 40];
    const int tid = threadIdx.x;
    const int wave = tid >> 6, lane = tid & 63, quad = lane >> 4, l16 = lane & 15;
    const int m0 = blockIdx.x * 128;
    const v4f Z = {0.f, 0.f, 0.f, 0.f};
    v4f acc[2][2] = {{Z, Z}, {Z, Z}};

    const int r = tid >> 1, half = tid & 1;
    const int m = m0 + r, bb_ = m >> 6, p = m & 63, py = p >> 3, px = p & 7;

    for (int kt = 0; kt < 576; ++kt) {
        const int k0 = kt * 32;
        const int tap = k0 >> 11, c0 = k0 & 2047;
        const int ky = tap / 3 - 1, kx = tap % 3 - 1;
        const int iy = py + ky, ix = px + kx;
        __syncthreads();
        uint4 d0 = {0, 0, 0, 0}, d1 = {0, 0, 0, 0};
        if ((unsigned)iy < 8u && (unsigned)ix < 8u) {
            const uint4* src = (const uint4*)(featT +
                ((size_t)(bb_ * 64 + iy * 8 + ix)) * 2048 + c0 + half * 16);
            d0 = src[0]; d1 = src[1];
        }
        *(uint4*)&As[r * 40 + half * 16] = d0;
        *(uint4*)&As[r * 40 + half * 16 + 8] = d1;
        if (tid < 64) {
            const int rB = tid >> 1, hB = tid & 1;
            const uint4* srcB = (const uint4*)(w2 + (size_t)rB * 18432 + k0 + hB * 16);
            *(uint4*)&Bs[rB * 40 + hB * 16] = srcB[0];
            *(uint4*)&Bs[rB * 40 + hB * 16 + 8] = srcB[1];
        }
        __syncthreads();
        v8s b0 = *(const v8s*)&Bs[l16 * 40 + quad * 8];
        v8s b1 = *(const v8s*)&Bs[(16 + l16) * 40 + quad * 8];
#pragma unroll
        for (int i = 0; i < 2; ++i) {
            v8s a = *(const v8s*)&As[(wave * 32 + i * 16 + l16) * 40 + quad * 8];
            acc[i][0] = MFMA(a, b0, acc[i][0]);
            acc[i][1] = MFMA(a, b1, acc[i][1]);
        }
    }
#pragma unroll
    for (int i = 0; i < 2; ++i)
#pragma unroll
        for (int j = 0; j < 2; ++j) {
            const int col = j * 16 + l16;
            const float bv = conv_b[col];
#pragma unroll
            for (int e = 0; e < 4; ++e) {
                const int row = m0 + wave * 32 + i * 16 + quad * 4 + e;
                const int ob = row >> 6, op = row & 63;
                out[ob * 2048 + col * 64 + op] = acc[i][j][e] + bv;
            }
        }
}

// ---------------------------------------------------------------------------
// Generic C[M][N] = A(M x K, row-major) * B(N x K, row-major)^T (+bias)(+relu)
// fp32 in/out, bf16 MFMA inside. N = gridDim.y*128 (multiple of 128).
// M arbitrary (clamp/mask). K % 4 == 0.
// ---------------------------------------------------------------------------
__global__ __launch_bounds__(256) void k_gemm_bt(
    const float* __restrict__ A, int lda,
    const float* __restrict__ B, int ldb, int boff,
    const float* __restrict__ bias,
    float* __restrict__ C, int ldc,
    int M, int K, int relu)
{
    __shared__ short As[128 * 40];
    __shared__ short Bs[128 * 40];
    const int tid = threadIdx.x;
    const int wave = tid >> 6, lane = tid & 63, quad = lane >> 4, l16 = lane & 15;
    const int wr = wave >> 1, wc = wave & 1;
    const int m0 = blockIdx.x * 128, n0 = blockIdx.y * 128;
    const v4f Z = {0.f, 0.f, 0.f, 0.f};
    v4f acc[4][4];
#pragma unroll
    for (int i = 0; i < 4; ++i)
#pragma unroll
        for (int j = 0; j < 4; ++j) acc[i][j] = Z;

    const int nkt = (K + 31) >> 5;
    const int rbase = tid >> 3, kq = tid & 7;
    for (int kt = 0; kt < nkt; ++kt) {
        const int k = (kt << 5) + kq * 4;
        const bool kv = (k + 3 < K);
        __syncthreads();
#pragma unroll
        for (int pass = 0; pass < 4; ++pass) {
            const int r = rbase + pass * 32;
            int ra = m0 + r; ra = ra < M ? ra : M - 1;
            float4 va = kv ? *(const float4*)(A + (size_t)ra * lda + k)
                           : make_float4(0.f, 0.f, 0.f, 0.f);
            *(uint2*)&As[r * 40 + kq * 4] = pack4(va.x, va.y, va.z, va.w);
            const int rb = n0 + r;
            float4 vb = kv ? *(const float4*)(B + (size_t)rb * ldb + boff + k)
                           : make_float4(0.f, 0.f, 0.f, 0.f);
            *(uint2*)&Bs[r * 40 + kq * 4] = pack4(vb.x, vb.y, vb.z, vb.w);
        }
        __syncthreads();
        v8s aF[4];
#pragma unroll
        for (int i = 0; i < 4; ++i)
            aF[i] = *(const v8s*)&As[(wr * 64 + i * 16 + l16) * 40 + quad * 8];
#pragma unroll
        for (int j = 0; j < 4; ++j) {
            v8s bF = *(const v8s*)&Bs[(wc * 64 + j * 16 + l16) * 40 + quad * 8];
#pragma unroll
            for (int i = 0; i < 4; ++i)
                acc[i][j] = MFMA(aF[i], bF, acc[i][j]);
        }
    }
#pragma unroll
    for (int i = 0; i < 4; ++i)
#pragma unroll
        for (int j = 0; j < 4; ++j) {
            const int col = n0 + wc * 64 + j * 16 + l16;
            const float bv = bias ? bias[col] : 0.0f;
#pragma unroll
            for (int e = 0; e < 4; ++e) {
                const int row = m0 + wr * 64 + i * 16 + quad * 4 + e;
                if (row < M) {
                    float v = acc[i][j][e] + bv;
                    if (relu) v = fmaxf(v, 0.0f);
                    C[(size_t)row * ldc + col] = v;
                }
            }
        }
}

// ---------------------------------------------------------------------------
// BatchNorm over batch dim: one block per column (512 cols, 256 rows)
// writes f and xcat[:, 512:1024]
// ---------------------------------------------------------------------------
__global__ __launch_bounds__(256) void k_bn(const float* __restrict__ f_pre,
                                            const float* __restrict__ g,
                                            const float* __restrict__ bb,
                                            float* __restrict__ f,
                                            float* __restrict__ xcat)
{
    __shared__ float red[8];
    const int col = blockIdx.x, tid = threadIdx.x;
    const int wave = tid >> 6, lane = tid & 63;
    float v = f_pre[tid * 512 + col];
    float s = v, q = v * v;
    for (int o = 32; o; o >>= 1) { s += __shfl_xor(s, o); q += __shfl_xor(q, o); }
    if (lane == 0) { red[wave] = s; red[4 + wave] = q; }
    __syncthreads();
    s = red[0] + red[1] + red[2] + red[3];
    q = red[4] + red[5] + red[6] + red[7];
    const float mu = s * (1.0f / 256.0f);
    const float var = q * (1.0f / 256.0f) - mu * mu;
    const float sc = rsqrtf(var + 1e-5f) * g[col];
    const float ov = (v - mu) * sc + bb[col];
    f[tid * 512 + col] = ov;
    xcat[tid * 1024 + 512 + col] = ov;
}

// ---------------------------------------------------------------------------
// Persistent GRU/attention scan: 256 blocks x 256 threads, grid barriers.
// ---------------------------------------------------------------------------
#define GBAR()                                                                  \
    do {                                                                        \
        bcount++;                                                               \
        __syncthreads();                                                        \
        if (tid == 0) {                                                         \
            __threadfence();                                                    \
            atomicAdd(bar, 1u);                                                 \
            const unsigned tgt = bcount * 256u;                                 \
            while (__hip_atomic_load(bar, __ATOMIC_RELAXED,                     \
                                     __HIP_MEMORY_SCOPE_AGENT) < tgt)           \
                __builtin_amdgcn_s_sleep(1);                                    \
            __threadfence();                                                    \
        }                                                                       \
        __syncthreads();                                                        \
    } while (0)

__global__ __launch_bounds__(256) void k_scan(
    const unsigned short* __restrict__ attn_wh,  // [512][512]
    const unsigned short* __restrict__ comb_wh,  // [512][512]
    const unsigned short* __restrict__ wih,      // [1536][512]
    const unsigned short* __restrict__ whh,      // [1536][512]
    const float* __restrict__ attn_b, const float* __restrict__ comb_b,
    const float* __restrict__ bih, const float* __restrict__ bhh,
    const float* __restrict__ ax,   // [9436][512]
    const float* __restrict__ cx,   // [9436][512]
    const float* __restrict__ f,    // [256][512]
    const float* __restrict__ states,
    const int* __restrict__ pack_idx,  // [256][48]
    const int* __restrict__ lengths,
    float* __restrict__ hx, unsigned short* __restrict__ hx_bf,
    float* __restrict__ logits,
    unsigned short* __restrict__ applied_bf,
    unsigned short* __restrict__ inp_bf,
    float* __restrict__ gh,          // [256][1536]
    float* __restrict__ hidd_out,    // d_out + 256
    float* __restrict__ xcat,        // [256][1024]
    unsigned* __restrict__ bar)
{
    __shared__ float red[8];
    const int tid = threadIdx.x, bid = blockIdx.x;
    const int wave = tid >> 6, lane = tid & 63, quad = lane >> 4, l16 = lane & 15;
    const v4f Z = {0.f, 0.f, 0.f, 0.f};
    unsigned bcount = 0;

    // init hx (row = bid) from states
    {
        float v0 = states[bid * 512 + tid], v1 = states[bid * 512 + 256 + tid];
        hx[bid * 512 + tid] = v0; hx[bid * 512 + 256 + tid] = v1;
        hx_bf[bid * 512 + tid] = f2bf(v0); hx_bf[bid * 512 + 256 + tid] = f2bf(v1);
    }
    GBAR();

    for (int t = 0; t < 48; ++t) {
        // ---- P1: logits (attn) and gh (gru h-gates), both from hx ----
        {
            const int nt = bid >> 1, mh = bid & 1;
            const bool isl = nt < 32;
            const unsigned short* W = isl ? attn_wh : whh;
            const int n0 = isl ? nt * 16 : (nt - 32) * 16;
            const int brow = n0 + l16;
            v4f a0 = Z, a1 = Z;
            const int r0 = mh * 128 + wave * 32 + l16;
            const int r1 = r0 + 16;
#pragma unroll
            for (int kt = 0; kt < 16; ++kt) {
                const int k = kt * 32 + quad * 8;
                v8s bF = *(const v8s*)&W[(size_t)brow * 512 + k];
                v8s aF0 = *(const v8s*)&hx_bf[(size_t)r0 * 512 + k];
                v8s aF1 = *(const v8s*)&hx_bf[(size_t)r1 * 512 + k];
                a0 = MFMA(aF0, bF, a0);
                a1 = MFMA(aF1, bF, a1);
            }
            const int col = n0 + l16;
#pragma unroll
            for (int i = 0; i < 2; ++i) {
                v4f av = i ? a1 : a0;
                const int rb = mh * 128 + wave * 32 + i * 16 + quad * 4;
                if (isl) {
                    const float bv = attn_b[col];
#pragma unroll
                    for (int e = 0; e < 4; ++e) {
                        const int row = rb + e;
                        float v = av[e] + bv;
                        const int pidx = pack_idx[row * 48 + t];
                        if (pidx >= 0) v += ax[(size_t)pidx * 512 + col];
                        logits[row * 512 + col] = v;
                    }
                } else {
                    const float bv = bhh[col];
#pragma unroll
                    for (int e = 0; e < 4; ++e) {
                        const int row = rb + e;
                        gh[row * 1536 + col] = av[e] + bv;
                    }
                }
            }
        }
        GBAR();
        // ---- P2: softmax + applied = f * aw (row = bid) ----
        {
            const int row = bid;
            const float l0v = logits[row * 512 + tid];
            const float l1v = logits[row * 512 + 256 + tid];
            float mx = fmaxf(l0v, l1v);
            for (int o = 32; o; o >>= 1) mx = fmaxf(mx, __shfl_xor(mx, o));
            if (lane == 0) red[wave] = mx;
            __syncthreads();
            mx = fmaxf(fmaxf(red[0], red[1]), fmaxf(red[2], red[3]));
            const float e0 = __expf(l0v - mx), e1 = __expf(l1v - mx);
            float sm = e0 + e1;
            for (int o = 32; o; o >>= 1) sm += __shfl_xor(sm, o);
            if (lane == 0) red[4 + wave] = sm;
            __syncthreads();
            const float inv = 1.0f / (red[4] + red[5] + red[6] + red[7]);
            applied_bf[row * 512 + tid] = f2bf(f[row * 512 + tid] * e0 * inv);
            applied_bf[row * 512 + 256 + tid] = f2bf(f[row * 512 + 256 + tid] * e1 * inv);
        }
        GBAR();
        // ---- P3: inp = relu(cx + applied @ comb_wh^T + comb_b) ----
        if (bid < 128) {
            const int nt = bid >> 2, mq = bid & 3;
            const int n0 = nt * 16;
            const int ar = mq * 64 + wave * 16 + l16;
            const int brow = n0 + l16;
            v4f acc = Z;
#pragma unroll
            for (int kt = 0; kt < 16; ++kt) {
                const int k = kt * 32 + quad * 8;
                v8s aF = *(const v8s*)&applied_bf[(size_t)ar * 512 + k];
                v8s bF = *(const v8s*)&comb_wh[(size_t)brow * 512 + k];
                acc = MFMA(aF, bF, acc);
            }
            const int col = n0 + l16;
            const float bv = comb_b[col];
#pragma unroll
            for (int e = 0; e < 4; ++e) {
                const int row = mq * 64 + wave * 16 + quad * 4 + e;
                float v = acc[e] + bv;
                const int pidx = pack_idx[row * 48 + t];
                if (pidx >= 0) v += cx[(size_t)pidx * 512 + col];
                inp_bf[row * 512 + col] = f2bf(fmaxf(v, 0.0f));
            }
        }
        GBAR();
        // ---- P4: gi = inp @ wih^T; gates; hx update; capture hiddens ----
        if (bid < 128) {
            const int cc = bid >> 2, mq = bid & 3;
            const int ar = mq * 64 + wave * 16 + l16;
            v4f g0 = Z, g1 = Z, g2 = Z;
#pragma unroll
            for (int kt = 0; kt < 16; ++kt) {
                const int k = kt * 32 + quad * 8;
                v8s aF = *(const v8s*)&inp_bf[(size_t)ar * 512 + k];
                v8s b0 = *(const v8s*)&wih[(size_t)(cc * 16 + l16) * 512 + k];
                v8s b1 = *(const v8s*)&wih[(size_t)(512 + cc * 16 + l16) * 512 + k];
                v8s b2 = *(const v8s*)&wih[(size_t)(1024 + cc * 16 + l16) * 512 + k];
                g0 = MFMA(aF, b0, g0);
                g1 = MFMA(aF, b1, g1);
                g2 = MFMA(aF, b2, g2);
            }
            const int col = cc * 16 + l16;
            const float br_ = bih[col], bz_ = bih[512 + col], bn_ = bih[1024 + col];
#pragma unroll
            for (int e = 0; e < 4; ++e) {
                const int row = mq * 64 + wave * 16 + quad * 4 + e;
                const float ghr = gh[row * 1536 + col];
                const float ghz = gh[row * 1536 + 512 + col];
                const float ghn = gh[row * 1536 + 1024 + col];
                const float rr = 1.0f / (1.0f + __expf(-(g0[e] + br_ + ghr)));
                const float zz = 1.0f / (1.0f + __expf(-(g1[e] + bz_ + ghz)));
                const float nn = tanhf(g2[e] + bn_ + rr * ghn);
                const float hold = hx[row * 512 + col];
                const float hnew = (1.0f - zz) * nn + zz * hold;
                hx[row * 512 + col] = hnew;
                hx_bf[row * 512 + col] = f2bf(hnew);
                if (t == lengths[row] - 1) {
                    hidd_out[row * 512 + col] = hnew;
                    xcat[row * 1024 + col] = hnew;
                }
            }
        }
        GBAR();
    }
}
#undef GBAR

// ---------------------------------------------------------------------------
// Final: out0[b] = sigmoid(y1[b] . lin3_w + lin3_b)
// ---------------------------------------------------------------------------
__global__ __launch_bounds__(256) void k_final(const float* __restrict__ y1,
                                               const float* __restrict__ w3,
                                               const float* __restrict__ b3,
                                               float* __restrict__ out0)
{
    __shared__ float red[4];
    const int row = blockIdx.x, tid = threadIdx.x;
    const int wave = tid >> 6, lane = tid & 63;
    float s = 0.f;
    for (int j = tid; j < 1024; j += 256) s += y1[row * 1024 + j] * w3[j];
    for (int o = 32; o; o >>= 1) s += __shfl_xor(s, o);
    if (lane == 0) red[wave] = s;
    __syncthreads();
    if (tid == 0) {
        float t = red[0] + red[1] + red[2] + red[3] + b3[0];
        out0[row] = 1.0f / (1.0f + __expf(-t));
    }
}

// ---------------------------------------------------------------------------
// Workspace layout (bytes)
// ---------------------------------------------------------------------------
static constexpr size_t OFF_FEATT  = 0;                            // 67,108,864
static constexpr size_t OFF_W2     = OFF_FEATT  + 67108864;        // 1,179,648
static constexpr size_t OFF_CONV   = OFF_W2     + 1179648;         // 2,097,152
static constexpr size_t OFF_FPRE   = OFF_CONV   + 2097152;         // 524,288
static constexpr size_t OFF_F      = OFF_FPRE   + 524288;          // 524,288
static constexpr size_t OFF_EMB    = OFF_F      + 524288;          // 19,324,928
static constexpr size_t OFF_AX     = OFF_EMB    + 19324928;        // 19,324,928
static constexpr size_t OFF_CX     = OFF_AX     + 19324928;        // 19,324,928
static constexpr size_t OFF_AWH    = OFF_CX     + 19324928;        // 524,288
static constexpr size_t OFF_CWH    = OFF_AWH    + 524288;          // 524,288
static constexpr size_t OFF_WIH    = OFF_CWH    + 524288;          // 1,572,864
static constexpr size_t OFF_WHH    = OFF_WIH    + 1572864;         // 1,572,864
static constexpr size_t OFF_LOGITS = OFF_WHH    + 1572864;         // 524,288
static constexpr size_t OFF_GH     = OFF_LOGITS + 524288;          // 1,572,864
static constexpr size_t OFF_APPL   = OFF_GH     + 1572864;         // 262,144
static constexpr size_t OFF_INP    = OFF_APPL   + 262144;          // 262,144
static constexpr size_t OFF_HX     = OFF_INP    + 262144;          // 524,288
static constexpr size_t OFF_HXBF   = OFF_HX     + 524288;          // 262,144
static constexpr size_t OFF_XCAT   = OFF_HXBF   + 262144;          // 1,048,576
static constexpr size_t OFF_Y1     = OFF_XCAT   + 1048576;         // 1,048,576
static constexpr size_t OFF_BAR    = OFF_Y1     + 1048576;         // 256
static constexpr size_t WS_NEED    = OFF_BAR + 256;                // ~139.1 MB

extern "C" void kernel_launch(void* const* d_in, const int* in_sizes, int n_in,
                              void* d_out, int out_size, void* d_ws, size_t ws_size,
                              hipStream_t stream)
{
    (void)in_sizes; (void)n_in; (void)out_size;
    if (ws_size < WS_NEED) return;  // fail visibly (output stays poisoned)

    const float* features = (const float*)d_in[0];
    const float* captions = (const float*)d_in[1];
    const float* states   = (const float*)d_in[2];
    const int*   pack_idx = (const int*)d_in[3];
    const int*   lengths  = (const int*)d_in[4];
    const float* conv_w   = (const float*)d_in[5];
    const float* conv_b   = (const float*)d_in[6];
    const float* fc_w     = (const float*)d_in[7];
    const float* fc_b     = (const float*)d_in[8];
    const float* bn_g     = (const float*)d_in[9];
    const float* bn_b     = (const float*)d_in[10];
    const float* fc2_w    = (const float*)d_in[11];
    const float* fc2_b    = (const float*)d_in[12];
    const float* attn_w   = (const float*)d_in[13];
    const float* attn_b   = (const float*)d_in[14];
    const float* comb_w   = (const float*)d_in[15];
    const float* comb_b   = (const float*)d_in[16];
    const float* gru_wih  = (const float*)d_in[17];
    const float* gru_whh  = (const float*)d_in[18];
    const float* gru_bih  = (const float*)d_in[19];
    const float* gru_bhh  = (const float*)d_in[20];
    const float* lin_w    = (const float*)d_in[21];
    const float* lin_b    = (const float*)d_in[22];
    const float* lin3_w   = (const float*)d_in[23];
    const float* lin3_b   = (const float*)d_in[24];

    char* W = (char*)d_ws;
    unsigned short* featT     = (unsigned short*)(W + OFF_FEATT);
    unsigned short* w2        = (unsigned short*)(W + OFF_W2);
    float* conv_flat          = (float*)(W + OFF_CONV);
    float* f_pre              = (float*)(W + OFF_FPRE);
    float* f_                 = (float*)(W + OFF_F);
    float* emb                = (float*)(W + OFF_EMB);
    float* ax                 = (float*)(W + OFF_AX);
    float* cx                 = (float*)(W + OFF_CX);
    unsigned short* awh       = (unsigned short*)(W + OFF_AWH);
    unsigned short* cwh       = (unsigned short*)(W + OFF_CWH);
    unsigned short* wih       = (unsigned short*)(W + OFF_WIH);
    unsigned short* whh       = (unsigned short*)(W + OFF_WHH);
    float* logits             = (float*)(W + OFF_LOGITS);
    float* gh                 = (float*)(W + OFF_GH);
    unsigned short* appl      = (unsigned short*)(W + OFF_APPL);
    unsigned short* inp       = (unsigned short*)(W + OFF_INP);
    float* hx                 = (float*)(W + OFF_HX);
    unsigned short* hx_bf     = (unsigned short*)(W + OFF_HXBF);
    float* xcat               = (float*)(W + OFF_XCAT);
    float* y1                 = (float*)(W + OFF_Y1);
    unsigned* bar             = (unsigned*)(W + OFF_BAR);

    float* out0 = (float*)d_out;
    float* out_hidden = out0 + 256;

    hipMemsetAsync(bar, 0, 256, stream);

    k_convert<<<10496, 256, 0, stream>>>(attn_w, comb_w, gru_wih, gru_whh, conv_w,
                                         awh, cwh, wih, whh, w2);
    k_tfeat<<<8192, 256, 0, stream>>>(features, featT);
    k_conv<<<128, 256, 0, stream>>>(featT, w2, conv_b, conv_flat);
    // fc: f_pre = conv_flat @ fc_w^T + fc_b    [256 x 512]
    k_gemm_bt<<<dim3(2, 4), 256, 0, stream>>>(conv_flat, 2048, fc_w, 2048, 0, fc_b,
                                              f_pre, 512, 256, 2048, 0);
    k_bn<<<512, 256, 0, stream>>>(f_pre, bn_g, bn_b, f_, xcat);
    // emb = captions @ fc2_w^T + fc2_b         [9436 x 512]
    k_gemm_bt<<<dim3(74, 4), 256, 0, stream>>>(captions, 10000, fc2_w, 10000, 0, fc2_b,
                                               emb, 512, 9436, 10000, 0);
    // ax = emb @ attn_w[:, :512]^T ; cx = emb @ comb_w[:, :512]^T
    k_gemm_bt<<<dim3(74, 4), 256, 0, stream>>>(emb, 512, attn_w, 1024, 0, nullptr,
                                               ax, 512, 9436, 512, 0);
    k_gemm_bt<<<dim3(74, 4), 256, 0, stream>>>(emb, 512, comb_w, 1024, 0, nullptr,
                                               cx, 512, 9436, 512, 0);
    k_scan<<<256, 256, 0, stream>>>(awh, cwh, wih, whh, attn_b, comb_b, gru_bih,
                                    gru_bhh, ax, cx, f_, states, pack_idx, lengths,
                                    hx, hx_bf, logits, appl, inp, gh,
                                    out_hidden, xcat, bar);
    // y1 = relu(xcat @ lin_w^T + lin_b)        [256 x 1024]
    k_gemm_bt<<<dim3(2, 8), 256, 0, stream>>>(xcat, 1024, lin_w, 1024, 0, lin_b,
                                              y1, 1024, 256, 1024, 1);
    k_final<<<256, 256, 0, stream>>>(y1, lin3_w, lin3_b, out0);
}

// Round 2
// 4863.214 us; speedup vs baseline: 1.5103x; 1.5103x over previous
//
#include <hip/hip_runtime.h>
#include <stdint.h>

typedef __attribute__((ext_vector_type(8))) short v8s;
typedef __attribute__((ext_vector_type(4))) float v4f;

#define MFMA(a, b, c) __builtin_amdgcn_mfma_f32_16x16x32_bf16((a), (b), (c), 0, 0, 0)

__device__ __forceinline__ unsigned short f2bf(float x) {
    unsigned u = __float_as_uint(x);
    return (unsigned short)((u + 0x7fffu + ((u >> 16) & 1u)) >> 16);
}
__device__ __forceinline__ uint2 pack4(float a, float b, float c, float d) {
    uint2 r;
    r.x = (unsigned)f2bf(a) | ((unsigned)f2bf(b) << 16);
    r.y = (unsigned)f2bf(c) | ((unsigned)f2bf(d) << 16);
    return r;
}

// Coherent (cross-XCD visible) access helpers: agent-scope relaxed atomics.
// These bypass stale L1/L2 (sc0 sc1) and write through to the coherence
// point WITHOUT any cache-invalidating fence -> read-only data stays hot in L2.
__device__ __forceinline__ float cloadf(const float* p) {
    return __hip_atomic_load(p, __ATOMIC_RELAXED, __HIP_MEMORY_SCOPE_AGENT);
}
__device__ __forceinline__ void cstoref(float* p, float v) {
    __hip_atomic_store(p, v, __ATOMIC_RELAXED, __HIP_MEMORY_SCOPE_AGENT);
}
__device__ __forceinline__ unsigned long long cload64(const void* p) {
    return __hip_atomic_load((const unsigned long long*)p, __ATOMIC_RELAXED,
                             __HIP_MEMORY_SCOPE_AGENT);
}
__device__ __forceinline__ void cstore32(void* p, unsigned v) {
    __hip_atomic_store((unsigned*)p, v, __ATOMIC_RELAXED, __HIP_MEMORY_SCOPE_AGENT);
}

// ---------------------------------------------------------------------------
// Weight conversion (unchanged)
// ---------------------------------------------------------------------------
__global__ __launch_bounds__(256) void k_convert(
    const float* __restrict__ attn_w, const float* __restrict__ comb_w,
    const float* __restrict__ gwih, const float* __restrict__ gwhh,
    const float* __restrict__ conv_w,
    unsigned short* __restrict__ awh, unsigned short* __restrict__ cwh,
    unsigned short* __restrict__ wih, unsigned short* __restrict__ whh,
    unsigned short* __restrict__ w2)
{
    const int S0 = 512 * 512;
    const int S1 = S0 + 512 * 512;
    const int S2 = S1 + 1536 * 512;
    const int S3 = S2 + 1536 * 512;
    const int S4 = S3 + 32 * 18432;
    for (int i = blockIdx.x * 256 + threadIdx.x; i < S4; i += gridDim.x * 256) {
        if (i < S0) {
            int n = i >> 9, k = i & 511;
            awh[i] = f2bf(attn_w[n * 1024 + 512 + k]);
        } else if (i < S1) {
            int j = i - S0; int n = j >> 9, k = j & 511;
            cwh[j] = f2bf(comb_w[n * 1024 + 512 + k]);
        } else if (i < S2) {
            int j = i - S1;
            wih[j] = f2bf(gwih[j]);
        } else if (i < S3) {
            int j = i - S2;
            whh[j] = f2bf(gwhh[j]);
        } else {
            int j = i - S3;
            int o = j / 18432, r = j - o * 18432;
            int tap = r >> 11, c = r & 2047;
            w2[j] = f2bf(conv_w[(o * 2048 + c) * 9 + tap]);
        }
    }
}

// ---------------------------------------------------------------------------
// features transpose (unchanged)
// ---------------------------------------------------------------------------
__global__ __launch_bounds__(256) void k_tfeat(const float* __restrict__ feat,
                                               unsigned short* __restrict__ featT)
{
    __shared__ float tile[64][65];
    const int b = blockIdx.x >> 5, c0 = (blockIdx.x & 31) << 6;
    for (int i = threadIdx.x; i < 4096; i += 256) {
        int cl = i >> 6, p = i & 63;
        tile[cl][p] = feat[((size_t)(b * 2048 + c0 + cl)) * 64 + p];
    }
    __syncthreads();
    for (int i = threadIdx.x; i < 4096; i += 256) {
        int pl = i >> 6, cl = i & 63;
        featT[((size_t)(b * 64 + pl)) * 2048 + c0 + cl] = f2bf(tile[cl][pl]);
    }
}

// ---------------------------------------------------------------------------
// Implicit-GEMM conv (unchanged)
// ---------------------------------------------------------------------------
__global__ __launch_bounds__(256) void k_conv(const unsigned short* __restrict__ featT,
                                              const unsigned short* __restrict__ w2,
                                              const float* __restrict__ conv_b,
                                              float* __restrict__ out)
{
    __shared__ short As[128 * 40];
    __shared__ short Bs[32 * 40];
    const int tid = threadIdx.x;
    const int wave = tid >> 6, lane = tid & 63, quad = lane >> 4, l16 = lane & 15;
    const int m0 = blockIdx.x * 128;
    const v4f Z = {0.f, 0.f, 0.f, 0.f};
    v4f acc[2][2] = {{Z, Z}, {Z, Z}};

    const int r = tid >> 1, half = tid & 1;
    const int m = m0 + r, bb_ = m >> 6, p = m & 63, py = p >> 3, px = p & 7;

    for (int kt = 0; kt < 576; ++kt) {
        const int k0 = kt * 32;
        const int tap = k0 >> 11, c0 = k0 & 2047;
        const int ky = tap / 3 - 1, kx = tap % 3 - 1;
        const int iy = py + ky, ix = px + kx;
        __syncthreads();
        uint4 d0 = {0, 0, 0, 0}, d1 = {0, 0, 0, 0};
        if ((unsigned)iy < 8u && (unsigned)ix < 8u) {
            const uint4* src = (const uint4*)(featT +
                ((size_t)(bb_ * 64 + iy * 8 + ix)) * 2048 + c0 + half * 16);
            d0 = src[0]; d1 = src[1];
        }
        *(uint4*)&As[r * 40 + half * 16] = d0;
        *(uint4*)&As[r * 40 + half * 16 + 8] = d1;
        if (tid < 64) {
            const int rB = tid >> 1, hB = tid & 1;
            const uint4* srcB = (const uint4*)(w2 + (size_t)rB * 18432 + k0 + hB * 16);
            *(uint4*)&Bs[rB * 40 + hB * 16] = srcB[0];
            *(uint4*)&Bs[rB * 40 + hB * 16 + 8] = srcB[1];
        }
        __syncthreads();
        v8s b0 = *(const v8s*)&Bs[l16 * 40 + quad * 8];
        v8s b1 = *(const v8s*)&Bs[(16 + l16) * 40 + quad * 8];
#pragma unroll
        for (int i = 0; i < 2; ++i) {
            v8s a = *(const v8s*)&As[(wave * 32 + i * 16 + l16) * 40 + quad * 8];
            acc[i][0] = MFMA(a, b0, acc[i][0]);
            acc[i][1] = MFMA(a, b1, acc[i][1]);
        }
    }
#pragma unroll
    for (int i = 0; i < 2; ++i)
#pragma unroll
        for (int j = 0; j < 2; ++j) {
            const int col = j * 16 + l16;
            const float bv = conv_b[col];
#pragma unroll
            for (int e = 0; e < 4; ++e) {
                const int row = m0 + wave * 32 + i * 16 + quad * 4 + e;
                const int ob = row >> 6, op = row & 63;
                out[ob * 2048 + col * 64 + op] = acc[i][j][e] + bv;
            }
        }
}

// ---------------------------------------------------------------------------
// Generic GEMM-BT (unchanged)
// ---------------------------------------------------------------------------
__global__ __launch_bounds__(256) void k_gemm_bt(
    const float* __restrict__ A, int lda,
    const float* __restrict__ B, int ldb, int boff,
    const float* __restrict__ bias,
    float* __restrict__ C, int ldc,
    int M, int K, int relu)
{
    __shared__ short As[128 * 40];
    __shared__ short Bs[128 * 40];
    const int tid = threadIdx.x;
    const int wave = tid >> 6, lane = tid & 63, quad = lane >> 4, l16 = lane & 15;
    const int wr = wave >> 1, wc = wave & 1;
    const int m0 = blockIdx.x * 128, n0 = blockIdx.y * 128;
    const v4f Z = {0.f, 0.f, 0.f, 0.f};
    v4f acc[4][4];
#pragma unroll
    for (int i = 0; i < 4; ++i)
#pragma unroll
        for (int j = 0; j < 4; ++j) acc[i][j] = Z;

    const int nkt = (K + 31) >> 5;
    const int rbase = tid >> 3, kq = tid & 7;
    for (int kt = 0; kt < nkt; ++kt) {
        const int k = (kt << 5) + kq * 4;
        const bool kv = (k + 3 < K);
        __syncthreads();
#pragma unroll
        for (int pass = 0; pass < 4; ++pass) {
            const int r = rbase + pass * 32;
            int ra = m0 + r; ra = ra < M ? ra : M - 1;
            float4 va = kv ? *(const float4*)(A + (size_t)ra * lda + k)
                           : make_float4(0.f, 0.f, 0.f, 0.f);
            *(uint2*)&As[r * 40 + kq * 4] = pack4(va.x, va.y, va.z, va.w);
            const int rb = n0 + r;
            float4 vb = kv ? *(const float4*)(B + (size_t)rb * ldb + boff + k)
                           : make_float4(0.f, 0.f, 0.f, 0.f);
            *(uint2*)&Bs[r * 40 + kq * 4] = pack4(vb.x, vb.y, vb.z, vb.w);
        }
        __syncthreads();
        v8s aF[4];
#pragma unroll
        for (int i = 0; i < 4; ++i)
            aF[i] = *(const v8s*)&As[(wr * 64 + i * 16 + l16) * 40 + quad * 8];
#pragma unroll
        for (int j = 0; j < 4; ++j) {
            v8s bF = *(const v8s*)&Bs[(wc * 64 + j * 16 + l16) * 40 + quad * 8];
#pragma unroll
            for (int i = 0; i < 4; ++i)
                acc[i][j] = MFMA(aF[i], bF, acc[i][j]);
        }
    }
#pragma unroll
    for (int i = 0; i < 4; ++i)
#pragma unroll
        for (int j = 0; j < 4; ++j) {
            const int col = n0 + wc * 64 + j * 16 + l16;
            const float bv = bias ? bias[col] : 0.0f;
#pragma unroll
            for (int e = 0; e < 4; ++e) {
                const int row = m0 + wr * 64 + i * 16 + quad * 4 + e;
                if (row < M) {
                    float v = acc[i][j][e] + bv;
                    if (relu) v = fmaxf(v, 0.0f);
                    C[(size_t)row * ldc + col] = v;
                }
            }
        }
}

// ---------------------------------------------------------------------------
// BatchNorm (unchanged)
// ---------------------------------------------------------------------------
__global__ __launch_bounds__(256) void k_bn(const float* __restrict__ f_pre,
                                            const float* __restrict__ g,
                                            const float* __restrict__ bb,
                                            float* __restrict__ f,
                                            float* __restrict__ xcat)
{
    __shared__ float red[8];
    const int col = blockIdx.x, tid = threadIdx.x;
    const int wave = tid >> 6, lane = tid & 63;
    float v = f_pre[tid * 512 + col];
    float s = v, q = v * v;
    for (int o = 32; o; o >>= 1) { s += __shfl_xor(s, o); q += __shfl_xor(q, o); }
    if (lane == 0) { red[wave] = s; red[4 + wave] = q; }
    __syncthreads();
    s = red[0] + red[1] + red[2] + red[3];
    q = red[4] + red[5] + red[6] + red[7];
    const float mu = s * (1.0f / 256.0f);
    const float var = q * (1.0f / 256.0f) - mu * mu;
    const float sc = rsqrtf(var + 1e-5f) * g[col];
    const float ov = (v - mu) * sc + bb[col];
    f[tid * 512 + col] = ov;
    xcat[tid * 1024 + 512 + col] = ov;
}

// ---------------------------------------------------------------------------
// Persistent GRU/attention scan v2: fence-free coherent barriers, L2 stays hot.
// 256 blocks x 256 threads, 1 block/CU guaranteed (grid == CU count).
// ---------------------------------------------------------------------------
#define GBAR()                                                                  \
    do {                                                                        \
        bcount++;                                                               \
        asm volatile("s_waitcnt vmcnt(0)" ::: "memory");                        \
        __syncthreads();                                                        \
        if (tid == 0) {                                                         \
            __hip_atomic_fetch_add(bar, 1u, __ATOMIC_RELAXED,                   \
                                   __HIP_MEMORY_SCOPE_AGENT);                   \
            const unsigned tgt = bcount * 256u;                                 \
            while (__hip_atomic_load(bar, __ATOMIC_RELAXED,                     \
                                     __HIP_MEMORY_SCOPE_AGENT) < tgt)           \
                __builtin_amdgcn_s_sleep(2);                                    \
        }                                                                       \
        __syncthreads();                                                        \
    } while (0)

__global__ __launch_bounds__(256) void k_scan(
    const unsigned short* __restrict__ awh,   // [512][512] attn hx-half
    const unsigned short* __restrict__ cwh,   // [512][512] comb applied-half
    const unsigned short* __restrict__ wih,   // [1536][512]
    const unsigned short* __restrict__ whh,   // [1536][512]
    const float* __restrict__ attn_b, const float* __restrict__ comb_b,
    const float* __restrict__ bih, const float* __restrict__ bhh,
    const float* __restrict__ ax,   // [9436][512]
    const float* __restrict__ cx,   // [9436][512]
    const float* __restrict__ f,    // [256][512]
    const float* __restrict__ states,
    const int* __restrict__ pack_idx,  // [256][48]
    const int* __restrict__ lengths,
    unsigned short* __restrict__ hx_bf,     // [256][512]
    float* __restrict__ logits,             // [256][512]
    unsigned short* __restrict__ appl,      // [256][512]
    unsigned short* __restrict__ inp,       // [256][512]
    float* __restrict__ gh,                 // [256][1536]
    float* __restrict__ hidd_out,           // d_out + 256
    float* __restrict__ xcat,               // [256][1024]
    unsigned* __restrict__ bar)
{
    // 32 rows x 520 shorts (512 data + 8 pad; 1040 B row stride, 16B aligned)
    __shared__ unsigned long long stg_u64[32 * 130];
    __shared__ float red[8];
    __shared__ unsigned short tr[1024];
    __shared__ float gacc[3][32][16];
    unsigned short* stg = (unsigned short*)stg_u64;

    const int tid = threadIdx.x, bid = blockIdx.x;
    const int wave = tid >> 6, lane = tid & 63, quad = lane >> 4, l16 = lane & 15;
    const v4f Z = {0.f, 0.f, 0.f, 0.f};
    unsigned bcount = 0;

    // P4 tile ownership: 32 col-groups (16 cols/gate) x 8 row-groups (32 rows)
    const int cg4 = bid & 31, rg4 = bid >> 5;
    const int r04 = rg4 * 32, cb4 = cg4 * 16;

    // hx fp32 state lives in registers: thread owns elements tid, tid+256 of
    // the 32x16 tile (row = el>>4, col = el&15).
    float hxr[2];
#pragma unroll
    for (int k2 = 0; k2 < 2; ++k2) {
        const int el = tid + k2 * 256;
        const int rl = el >> 4, cl = el & 15;
        hxr[k2] = states[(r04 + rl) * 512 + cb4 + cl];
        tr[el] = f2bf(hxr[k2]);
    }
    __syncthreads();
    {
        const int rl = tid >> 3, pr = tid & 7;
        cstore32(hx_bf + (r04 + rl) * 512 + cb4 + pr * 2,
                 *(const unsigned*)&tr[rl * 16 + pr * 2]);
    }
    GBAR();

    for (int t = 0; t < 48; ++t) {
        // ---- P1: logits (attn cols 0-511) + gh (whh cols 512-2047) --------
        // 32 col-tiles (64) x 8 row-groups (32); wave = 16-col slice.
        {
            const int ct = bid & 31, rg = bid >> 5;
            const int gc0 = ct * 64, r0 = rg * 32;
            {   // stage hx_bf rows r0..r0+31 into LDS (coherent 8B loads)
                const int r = tid >> 3, seg = tid & 7;
                const unsigned short* src = hx_bf + (r0 + r) * 512 + seg * 64;
                unsigned long long* dst = stg_u64 + r * 130 + seg * 16;
#pragma unroll
                for (int j = 0; j < 16; ++j) dst[j] = cload64(src + j * 4);
            }
            __syncthreads();
            const bool isl = gc0 < 512;
            const unsigned short* Wp = isl ? awh : whh;
            const int wc = (isl ? gc0 : gc0 - 512) + wave * 16 + l16;
            v4f a0 = Z, a1 = Z;
#pragma unroll
            for (int kt = 0; kt < 16; ++kt) {
                const int k = kt * 32 + quad * 8;
                v8s bF = *(const v8s*)&Wp[(size_t)wc * 512 + k];
                v8s f0 = *(const v8s*)&stg[l16 * 520 + k];
                v8s f1 = *(const v8s*)&stg[(16 + l16) * 520 + k];
                a0 = MFMA(f0, bF, a0);
                a1 = MFMA(f1, bF, a1);
            }
            const int col = gc0 + wave * 16 + l16;
            if (isl) {
                const float bv = attn_b[col];
#pragma unroll
                for (int ms = 0; ms < 2; ++ms) {
                    const v4f av = ms ? a1 : a0;
#pragma unroll
                    for (int e = 0; e < 4; ++e) {
                        const int row = r0 + ms * 16 + quad * 4 + e;
                        float v = av[e] + bv;
                        const int pidx = pack_idx[row * 48 + t];
                        if (pidx >= 0) v += ax[(size_t)pidx * 512 + col];
                        cstoref(&logits[row * 512 + col], v);
                    }
                }
            } else {
                const int colw = col - 512;
                const float bv = bhh[colw];
#pragma unroll
                for (int ms = 0; ms < 2; ++ms) {
                    const v4f av = ms ? a1 : a0;
#pragma unroll
                    for (int e = 0; e < 4; ++e) {
                        const int row = r0 + ms * 16 + quad * 4 + e;
                        cstoref(&gh[row * 1536 + colw], av[e] + bv);
                    }
                }
            }
        }
        GBAR();
        // ---- P2: softmax + applied = f * aw (row = bid) -------------------
        {
            const int r = bid, c0 = tid * 2;
            const float l0 = cloadf(&logits[r * 512 + c0]);
            const float l1 = cloadf(&logits[r * 512 + c0 + 1]);
            float mx = fmaxf(l0, l1);
            for (int o = 32; o; o >>= 1) mx = fmaxf(mx, __shfl_xor(mx, o));
            if (lane == 0) red[wave] = mx;
            __syncthreads();
            mx = fmaxf(fmaxf(red[0], red[1]), fmaxf(red[2], red[3]));
            const float e0 = __expf(l0 - mx), e1 = __expf(l1 - mx);
            float sm = e0 + e1;
            for (int o = 32; o; o >>= 1) sm += __shfl_xor(sm, o);
            if (lane == 0) red[4 + wave] = sm;
            __syncthreads();
            const float inv = 1.0f / (red[4] + red[5] + red[6] + red[7]);
            const unsigned pk =
                (unsigned)f2bf(f[r * 512 + c0] * e0 * inv) |
                ((unsigned)f2bf(f[r * 512 + c0 + 1] * e1 * inv) << 16);
            cstore32(appl + r * 512 + c0, pk);
        }
        GBAR();
        // ---- P3: inp = relu(cx_t + applied @ cwh^T + comb_b) --------------
        // 16 col-tiles (32) x 8 row-groups (32) = 128 blocks; wave=(ms,ns).
        if (bid < 128) {
            const int ct = bid & 15, rg = bid >> 4;
            const int c0 = ct * 32, r0 = rg * 32;
            {
                const int r = tid >> 3, seg = tid & 7;
                const unsigned short* src = appl + (r0 + r) * 512 + seg * 64;
                unsigned long long* dst = stg_u64 + r * 130 + seg * 16;
#pragma unroll
                for (int j = 0; j < 16; ++j) dst[j] = cload64(src + j * 4);
            }
            __syncthreads();
            const int ms = wave & 1, ns = wave >> 1;
            const int colw = c0 + ns * 16 + l16;
            v4f acc = Z;
#pragma unroll
            for (int kt = 0; kt < 16; ++kt) {
                const int k = kt * 32 + quad * 8;
                v8s bF = *(const v8s*)&cwh[(size_t)colw * 512 + k];
                v8s fA = *(const v8s*)&stg[(ms * 16 + l16) * 520 + k];
                acc = MFMA(fA, bF, acc);
            }
            const float bv = comb_b[colw];
#pragma unroll
            for (int e = 0; e < 4; ++e) {
                const int rl = ms * 16 + quad * 4 + e;
                const int row = r0 + rl;
                float v = acc[e] + bv;
                const int pidx = pack_idx[row * 48 + t];
                if (pidx >= 0) v += cx[(size_t)pidx * 512 + colw];
                tr[rl * 32 + ns * 16 + l16] = f2bf(fmaxf(v, 0.0f));
            }
            __syncthreads();
#pragma unroll
            for (int k2 = 0; k2 < 2; ++k2) {
                const int i = tid + k2 * 256;
                const int rl = i >> 4, pr = i & 15;
                cstore32(inp + (r0 + rl) * 512 + c0 + pr * 2,
                         *(const unsigned*)&tr[rl * 32 + pr * 2]);
            }
        }
        GBAR();
        // ---- P4: gi = inp @ wih^T; gates; hx update -----------------------
        {
            {
                const int r = tid >> 3, seg = tid & 7;
                const unsigned short* src = inp + (r04 + r) * 512 + seg * 64;
                unsigned long long* dst = stg_u64 + r * 130 + seg * 16;
#pragma unroll
                for (int j = 0; j < 16; ++j) dst[j] = cload64(src + j * 4);
            }
            __syncthreads();
            // wave0: gate r (ms 0,1); wave1: gate z (ms 0,1);
            // wave2: gate n ms0; wave3: gate n ms1.
            const int ug = (wave < 2) ? wave : 2;
            const bool two = (wave < 2);
            const int msb = (wave == 3) ? 1 : 0;
            const size_t wrow = (size_t)(ug * 512 + cb4 + l16) * 512;
            v4f pa0 = Z, pa1 = Z;
#pragma unroll
            for (int kt = 0; kt < 16; ++kt) {
                const int k = kt * 32 + quad * 8;
                v8s bF = *(const v8s*)&wih[wrow + k];
                if (two) {
                    v8s f0 = *(const v8s*)&stg[l16 * 520 + k];
                    v8s f1 = *(const v8s*)&stg[(16 + l16) * 520 + k];
                    pa0 = MFMA(f0, bF, pa0);
                    pa1 = MFMA(f1, bF, pa1);
                } else {
                    v8s f0 = *(const v8s*)&stg[(msb * 16 + l16) * 520 + k];
                    pa0 = MFMA(f0, bF, pa0);
                }
            }
            if (two) {
#pragma unroll
                for (int e = 0; e < 4; ++e) {
                    gacc[ug][quad * 4 + e][l16] = pa0[e];
                    gacc[ug][16 + quad * 4 + e][l16] = pa1[e];
                }
            } else {
#pragma unroll
                for (int e = 0; e < 4; ++e)
                    gacc[2][msb * 16 + quad * 4 + e][l16] = pa0[e];
            }
            __syncthreads();
#pragma unroll
            for (int k2 = 0; k2 < 2; ++k2) {
                const int el = tid + k2 * 256;
                const int rl = el >> 4, cl = el & 15;
                const int row = r04 + rl, col = cb4 + cl;
                const float gir = gacc[0][rl][cl] + bih[col];
                const float giz = gacc[1][rl][cl] + bih[512 + col];
                const float gin = gacc[2][rl][cl] + bih[1024 + col];
                const float ghr = cloadf(&gh[row * 1536 + col]);
                const float ghz = cloadf(&gh[row * 1536 + 512 + col]);
                const float ghn = cloadf(&gh[row * 1536 + 1024 + col]);
                const float rr = 1.0f / (1.0f + __expf(-(gir + ghr)));
                const float zz = 1.0f / (1.0f + __expf(-(giz + ghz)));
                const float nn = tanhf(gin + rr * ghn);
                const float hnew = (1.0f - zz) * nn + zz * hxr[k2];
                hxr[k2] = hnew;
                tr[el] = f2bf(hnew);
                if (t == lengths[row] - 1) {
                    hidd_out[row * 512 + col] = hnew;
                    xcat[row * 1024 + col] = hnew;
                }
            }
            __syncthreads();
            {
                const int rl = tid >> 3, pr = tid & 7;
                cstore32(hx_bf + (r04 + rl) * 512 + cb4 + pr * 2,
                         *(const unsigned*)&tr[rl * 16 + pr * 2]);
            }
        }
        GBAR();
    }
}
#undef GBAR

// ---------------------------------------------------------------------------
// Final head (unchanged)
// ---------------------------------------------------------------------------
__global__ __launch_bounds__(256) void k_final(const float* __restrict__ y1,
                                               const float* __restrict__ w3,
                                               const float* __restrict__ b3,
                                               float* __restrict__ out0)
{
    __shared__ float red[4];
    const int row = blockIdx.x, tid = threadIdx.x;
    const int wave = tid >> 6, lane = tid & 63;
    float s = 0.f;
    for (int j = tid; j < 1024; j += 256) s += y1[row * 1024 + j] * w3[j];
    for (int o = 32; o; o >>= 1) s += __shfl_xor(s, o);
    if (lane == 0) red[wave] = s;
    __syncthreads();
    if (tid == 0) {
        float t = red[0] + red[1] + red[2] + red[3] + b3[0];
        out0[row] = 1.0f / (1.0f + __expf(-t));
    }
}

// ---------------------------------------------------------------------------
// Workspace layout (bytes)
// ---------------------------------------------------------------------------
static constexpr size_t OFF_FEATT  = 0;
static constexpr size_t OFF_W2     = OFF_FEATT  + 67108864;
static constexpr size_t OFF_CONV   = OFF_W2     + 1179648;
static constexpr size_t OFF_FPRE   = OFF_CONV   + 2097152;
static constexpr size_t OFF_F      = OFF_FPRE   + 524288;
static constexpr size_t OFF_EMB    = OFF_F      + 524288;
static constexpr size_t OFF_AX     = OFF_EMB    + 19324928;
static constexpr size_t OFF_CX     = OFF_AX     + 19324928;
static constexpr size_t OFF_AWH    = OFF_CX     + 19324928;
static constexpr size_t OFF_CWH    = OFF_AWH    + 524288;
static constexpr size_t OFF_WIH    = OFF_CWH    + 524288;
static constexpr size_t OFF_WHH    = OFF_WIH    + 1572864;
static constexpr size_t OFF_LOGITS = OFF_WHH    + 1572864;
static constexpr size_t OFF_GH     = OFF_LOGITS + 524288;
static constexpr size_t OFF_APPL   = OFF_GH     + 1572864;
static constexpr size_t OFF_INP    = OFF_APPL   + 262144;
static constexpr size_t OFF_HXBF   = OFF_INP    + 262144;
static constexpr size_t OFF_XCAT   = OFF_HXBF   + 262144;
static constexpr size_t OFF_Y1     = OFF_XCAT   + 1048576;
static constexpr size_t OFF_BAR    = OFF_Y1     + 1048576;
static constexpr size_t WS_NEED    = OFF_BAR + 256;

extern "C" void kernel_launch(void* const* d_in, const int* in_sizes, int n_in,
                              void* d_out, int out_size, void* d_ws, size_t ws_size,
                              hipStream_t stream)
{
    (void)in_sizes; (void)n_in; (void)out_size;
    if (ws_size < WS_NEED) return;

    const float* features = (const float*)d_in[0];
    const float* captions = (const float*)d_in[1];
    const float* states   = (const float*)d_in[2];
    const int*   pack_idx = (const int*)d_in[3];
    const int*   lengths  = (const int*)d_in[4];
    const float* conv_w   = (const float*)d_in[5];
    const float* conv_b   = (const float*)d_in[6];
    const float* fc_w     = (const float*)d_in[7];
    const float* fc_b     = (const float*)d_in[8];
    const float* bn_g     = (const float*)d_in[9];
    const float* bn_b     = (const float*)d_in[10];
    const float* fc2_w    = (const float*)d_in[11];
    const float* fc2_b    = (const float*)d_in[12];
    const float* attn_w   = (const float*)d_in[13];
    const float* attn_b   = (const float*)d_in[14];
    const float* comb_w   = (const float*)d_in[15];
    const float* comb_b   = (const float*)d_in[16];
    const float* gru_wih  = (const float*)d_in[17];
    const float* gru_whh  = (const float*)d_in[18];
    const float* gru_bih  = (const float*)d_in[19];
    const float* gru_bhh  = (const float*)d_in[20];
    const float* lin_w    = (const float*)d_in[21];
    const float* lin_b    = (const float*)d_in[22];
    const float* lin3_w   = (const float*)d_in[23];
    const float* lin3_b   = (const float*)d_in[24];

    char* W = (char*)d_ws;
    unsigned short* featT     = (unsigned short*)(W + OFF_FEATT);
    unsigned short* w2        = (unsigned short*)(W + OFF_W2);
    float* conv_flat          = (float*)(W + OFF_CONV);
    float* f_pre              = (float*)(W + OFF_FPRE);
    float* f_                 = (float*)(W + OFF_F);
    float* emb                = (float*)(W + OFF_EMB);
    float* ax                 = (float*)(W + OFF_AX);
    float* cx                 = (float*)(W + OFF_CX);
    unsigned short* awh       = (unsigned short*)(W + OFF_AWH);
    unsigned short* cwh       = (unsigned short*)(W + OFF_CWH);
    unsigned short* wih       = (unsigned short*)(W + OFF_WIH);
    unsigned short* whh       = (unsigned short*)(W + OFF_WHH);
    float* logits             = (float*)(W + OFF_LOGITS);
    float* gh                 = (float*)(W + OFF_GH);
    unsigned short* appl      = (unsigned short*)(W + OFF_APPL);
    unsigned short* inp       = (unsigned short*)(W + OFF_INP);
    unsigned short* hx_bf     = (unsigned short*)(W + OFF_HXBF);
    float* xcat               = (float*)(W + OFF_XCAT);
    float* y1                 = (float*)(W + OFF_Y1);
    unsigned* bar             = (unsigned*)(W + OFF_BAR);

    float* out0 = (float*)d_out;
    float* out_hidden = out0 + 256;

    hipMemsetAsync(bar, 0, 256, stream);

    k_convert<<<10496, 256, 0, stream>>>(attn_w, comb_w, gru_wih, gru_whh, conv_w,
                                         awh, cwh, wih, whh, w2);
    k_tfeat<<<8192, 256, 0, stream>>>(features, featT);
    k_conv<<<128, 256, 0, stream>>>(featT, w2, conv_b, conv_flat);
    k_gemm_bt<<<dim3(2, 4), 256, 0, stream>>>(conv_flat, 2048, fc_w, 2048, 0, fc_b,
                                              f_pre, 512, 256, 2048, 0);
    k_bn<<<512, 256, 0, stream>>>(f_pre, bn_g, bn_b, f_, xcat);
    k_gemm_bt<<<dim3(74, 4), 256, 0, stream>>>(captions, 10000, fc2_w, 10000, 0, fc2_b,
                                               emb, 512, 9436, 10000, 0);
    k_gemm_bt<<<dim3(74, 4), 256, 0, stream>>>(emb, 512, attn_w, 1024, 0, nullptr,
                                               ax, 512, 9436, 512, 0);
    k_gemm_bt<<<dim3(74, 4), 256, 0, stream>>>(emb, 512, comb_w, 1024, 0, nullptr,
                                               cx, 512, 9436, 512, 0);
    k_scan<<<256, 256, 0, stream>>>(awh, cwh, wih, whh, attn_b, comb_b, gru_bih,
                                    gru_bhh, ax, cx, f_, states, pack_idx, lengths,
                                    hx_bf, logits, appl, inp, gh,
                                    out_hidden, xcat, bar);
    k_gemm_bt<<<dim3(2, 8), 256, 0, stream>>>(xcat, 1024, lin_w, 1024, 0, lin_b,
                                              y1, 1024, 256, 1024, 1);
    k_final<<<256, 256, 0, stream>>>(y1, lin3_w, lin3_b, out0);
}